// Round 2
// baseline (313.341 us; speedup 1.0000x reference)
//
#include <hip/hip_runtime.h>
#include <cstdint>

// Problem constants (B,C,D,H,W) = (4,1,192,192,192)
#define NB    4
#define DD    192
#define HH    192
#define WW    192
#define WPR   6                         // 32-bit words per W-row (192/32)
#define NPB   (DD*HH*WW)                // 7,077,888 voxels per batch
#define NWORDS (NB*DD*HH*WPR)           // 884,736 packed words total
#define W_CONN 1e-4f

// ---------------- Kernel 1: BCE partial sums + pred bit-pack ----------------
// One thread per 32 consecutive W-voxels (one packed word). Block = 256
// threads = 8192 voxels, which divides NPB exactly -> block is batch-uniform.
__global__ __launch_bounds__(256) void k_bce_pack(
    const float* __restrict__ x, const float* __restrict__ y,
    uint32_t* __restrict__ bits, float* __restrict__ bce_sum)
{
    const int w = blockIdx.x * 256 + threadIdx.x;      // word id < NWORDS
    const long base = (long)w * 32;
    const float4* __restrict__ x4 = reinterpret_cast<const float4*>(x + base);
    const float4* __restrict__ y4 = reinterpret_cast<const float4*>(y + base);

    float s = 0.0f;
    uint32_t m = 0;
#pragma unroll
    for (int j = 0; j < 8; ++j) {
        const float4 xv = x4[j];
        const float4 yv = y4[j];
        {   float xi = xv.x, yi = yv.x;
            s += fmaxf(xi, 0.0f) - xi * yi + log1pf(__expf(-fabsf(xi)));
            m |= (xi > 0.0f ? 1u : 0u) << (4 * j + 0); }
        {   float xi = xv.y, yi = yv.y;
            s += fmaxf(xi, 0.0f) - xi * yi + log1pf(__expf(-fabsf(xi)));
            m |= (xi > 0.0f ? 1u : 0u) << (4 * j + 1); }
        {   float xi = xv.z, yi = yv.z;
            s += fmaxf(xi, 0.0f) - xi * yi + log1pf(__expf(-fabsf(xi)));
            m |= (xi > 0.0f ? 1u : 0u) << (4 * j + 2); }
        {   float xi = xv.w, yi = yv.w;
            s += fmaxf(xi, 0.0f) - xi * yi + log1pf(__expf(-fabsf(xi)));
            m |= (xi > 0.0f ? 1u : 0u) << (4 * j + 3); }
    }
    bits[w] = m;

    // block reduction (float)
    __shared__ float red[256];
    red[threadIdx.x] = s;
    __syncthreads();
#pragma unroll
    for (int off = 128; off > 0; off >>= 1) {
        if (threadIdx.x < off) red[threadIdx.x] += red[threadIdx.x + off];
        __syncthreads();
    }
    if (threadIdx.x == 0) {
        const int b = (int)(base / (long)NPB);         // uniform per block
        atomicAdd(&bce_sum[b], red[0]);
    }
}

// ---------------- Kernel 2: connectivity via bitwise 26-neighbor OR ---------
// Voxel passes iff all 26 periodic neighbors have pred==0
// (acc==pred  <=>  sum of the 26 non-center box entries == 0).
__global__ __launch_bounds__(256) void k_conn(
    const uint32_t* __restrict__ bits, unsigned int* __restrict__ conn_cnt)
{
    const int w = blockIdx.x * 256 + threadIdx.x;      // word id < NWORDS
    const int wi  = w % WPR;
    const int t1  = w / WPR;
    const int yy  = t1 % HH;
    const int t2  = t1 / HH;
    const int zz  = t2 % DD;
    const int b   = t2 / DD;

    const int wiL = (wi == 0)       ? (WPR - 1) : (wi - 1);
    const int wiR = (wi == WPR - 1) ? 0         : (wi + 1);

    const uint32_t* __restrict__ bb = bits + (long)b * (DD * HH * WPR);

    uint32_t n26 = 0;
#pragma unroll
    for (int dz = -1; dz <= 1; ++dz) {
#pragma unroll
        for (int dy = -1; dy <= 1; ++dy) {
            int z2 = zz + dz; if (z2 < 0) z2 += DD; if (z2 >= DD) z2 -= DD;
            int y2 = yy + dy; if (y2 < 0) y2 += HH; if (y2 >= HH) y2 -= HH;
            const uint32_t* row = bb + ((long)z2 * HH + y2) * WPR;
            const uint32_t c = row[wi];
            const uint32_t l = row[wiL];
            const uint32_t r = row[wiR];
            // bit i gets row[i-1] and row[i+1] (periodic across word bounds)
            uint32_t o = ((c << 1) | (l >> 31)) | ((c >> 1) | (r << 31));
            if (!(dz == 0 && dy == 0)) o |= c;         // center row excludes self
            n26 |= o;
        }
    }
    int cnt = 32 - __popc(n26);                        // voxels passing in word

    __shared__ int red[256];
    red[threadIdx.x] = cnt;
    __syncthreads();
#pragma unroll
    for (int off = 128; off > 0; off >>= 1) {
        if (threadIdx.x < off) red[threadIdx.x] += red[threadIdx.x + off];
        __syncthreads();
    }
    if (threadIdx.x == 0) {
        atomicAdd(&conn_cnt[b], (unsigned int)red[0]);
    }
}

// ---------------- Kernel 3: final combine -----------------------------------
__global__ void k_final(const float* __restrict__ is_gt,
                        const float* __restrict__ bce_sum,
                        const unsigned int* __restrict__ conn_cnt,
                        float* __restrict__ out)
{
    if (threadIdx.x == 0 && blockIdx.x == 0) {
        const float inv = 1.0f / (float)NPB;
        float loss = 0.0f;
#pragma unroll
        for (int b = 0; b < NB; ++b) {
            loss += is_gt[b] * (bce_sum[b] * inv)
                  + W_CONN  * ((float)conn_cnt[b] * inv);
        }
        out[0] = loss;
    }
}

extern "C" void kernel_launch(void* const* d_in, const int* in_sizes, int n_in,
                              void* d_out, int out_size, void* d_ws, size_t ws_size,
                              hipStream_t stream) {
    const float* x     = (const float*)d_in[0];
    const float* y     = (const float*)d_in[1];
    const float* is_gt = (const float*)d_in[2];
    float* out = (float*)d_out;

    char* ws = (char*)d_ws;
    float*        bce_sum  = (float*)ws;               // 16 B
    unsigned int* conn_cnt = (unsigned int*)(ws + 64); // 16 B
    uint32_t*     bits     = (uint32_t*)(ws + 256);    // 3.54 MB

    // zero the accumulators (capture-legal)
    hipMemsetAsync(ws, 0, 256, stream);

    const int blocks = NWORDS / 256;                   // 3456
    k_bce_pack<<<blocks, 256, 0, stream>>>(x, y, bits, bce_sum);
    k_conn   <<<blocks, 256, 0, stream>>>(bits, conn_cnt);
    k_final  <<<1, 64, 0, stream>>>(is_gt, bce_sum, conn_cnt, out);
}